// Round 5
// baseline (287.703 us; speedup 1.0000x reference)
//
#include <hip/hip_runtime.h>

#define BB 16
#define HH 256
#define WW 256
#define CC 16
#define HID 128
#define TS 16
#define NPIX ((size_t)BB * HH * WW)
#define KEXP 160   // 9 taps x 16 ch = 144, padded to 160 (tap 9 = zero weights)
#define XSTR 24    // xt pixel stride in bf16 (16 ch + 8 pad, 48 B)
#define HSTR 136   // H row stride in bf16 (128 + 8; 68 dwords = 4 mod 32 -> clean bank tiling)

typedef __attribute__((ext_vector_type(8))) short short8;
typedef __attribute__((ext_vector_type(4))) float floatx4;

__device__ inline unsigned int f2bf(float f) {
    unsigned int u = __float_as_uint(f);
    return (u + 0x7FFFu + ((u >> 16) & 1u)) >> 16;   // RNE (prep only)
}
// truncating bf16x2 pack: one v_perm_b32. mem order: lo then hi.
__device__ inline unsigned int packtr(float lo, float hi) {
    return __builtin_amdgcn_perm(__float_as_uint(hi), __float_as_uint(lo), 0x07060302u);
}

// ---------------------------------------------------------------------------
// prep: w0e[n][t*16+c] = sobel-folded first-layer weights (128 x 160 bf16,
// cols 144..159 zero). w1b[o][c_hid] = 16 x 128 bf16.
// ---------------------------------------------------------------------------
__global__ void prep(const float* __restrict__ w0, const float* __restrict__ w1,
                     unsigned short* __restrict__ w0e, unsigned short* __restrict__ w1b) {
    int i = blockIdx.x * blockDim.x + threadIdx.x;
    if (i < HID * KEXP) {
        int n = i / KEXP, k = i % KEXP;
        int t = k >> 4, c = k & 15;
        float v = 0.f;
        if (t < 9) {
            int dy = t / 3, dx = t % 3;
            float id = (t == 4) ? 1.f : 0.f;
            float sx = (float)(dx - 1) * ((dy == 1) ? 2.f : 1.f) * 0.125f;
            float sy = (float)(dy - 1) * ((dx == 1) ? 2.f : 1.f) * 0.125f;
            v = w0[n * 48 + 3 * c] * id + w0[n * 48 + 3 * c + 1] * sx
              + w0[n * 48 + 3 * c + 2] * sy;
        }
        w0e[i] = (unsigned short)f2bf(v);
    }
    if (i < CC * HID) w1b[i] = (unsigned short)f2bf(w1[i]);
}

// ---------------------------------------------------------------------------
// pass1: nt-outer / q-inner. Per nt: 5 B-gathers once, 4 hidden-quarters of
// GEMM1 (A reloaded from global, L1/L2-hot), all H -> per-wave LDS buffer,
// ONE lgkm drain, then GEMM2 as 4 MFMA over K=128, epilogue per nt.
// C/D layout: col=lane&15, row=quad*4+reg (m89/m91-verified)
// LDS: xt 15552 + at 1296 + Hb 17408 = 34256 B -> 4 blocks/CU (w/ VGPR<=128)
// ---------------------------------------------------------------------------
__global__ __launch_bounds__(256, 4)
void pass1(const float* __restrict__ x, const unsigned short* __restrict__ w0e,
           const unsigned short* __restrict__ w1b, const float* __restrict__ rand_mask,
           float* __restrict__ xn_out, float* __restrict__ alpha_out,
           float* __restrict__ pre_out)
{
    __shared__ unsigned short xt[18 * 18 * XSTR];          // bf16 halo tile
    __shared__ float at[18 * 18];                          // alpha (ch3) fp32 plane
    __shared__ unsigned short Hb[4][16 * HSTR];            // per-wave H buffer [16px][136]

    const int tx = threadIdx.x, ty = threadIdx.y;
    const int bx = blockIdx.x * TS, by = blockIdx.y * TS, b = blockIdx.z;
    const int tid = ty * TS + tx;
    const float* xb = x + (size_t)b * HH * WW * CC;

    // ---- stage halo tile: fp32 global -> bf16 LDS (+ alpha plane) ----
    for (int idx = tid; idx < 18 * 18 * 4; idx += 256) {
        int cq = idx & 3, p = idx >> 2;
        int lyy = p / 18, lxx = p % 18;
        int gy = by + lyy - 1, gx = bx + lxx - 1;
        float4 v = make_float4(0.f, 0.f, 0.f, 0.f);
        if (gy >= 0 && gy < HH && gx >= 0 && gx < WW)
            v = *(const float4*)(xb + (size_t)(gy * WW + gx) * CC + cq * 4);
        *(uint2*)(xt + p * XSTR + cq * 4) = make_uint2(packtr(v.x, v.y), packtr(v.z, v.w));
        if (cq == 0) at[p] = v.w;   // channel 3
    }
    __syncthreads();

    // ---- pre_life: 3x3 max of alpha > 0.1 ----
    {
        float m = -1.f;
        #pragma unroll
        for (int dy = 0; dy < 3; ++dy) {
            const float* r = at + (ty + dy) * 18 + tx;
            m = fmaxf(m, fmaxf(fmaxf(r[0], r[1]), r[2]));
        }
        const size_t pix0 = (size_t)b * HH * WW + (size_t)(by + ty) * WW + (bx + tx);
        pre_out[pix0] = (m > 0.1f) ? 1.f : 0.f;
    }

    // ---- MFMA phase: wave w owns pixels [64w, 64w+64), 4 nt-tiles of 16 ----
    const int w = tid >> 6, lane = tid & 63;
    const int quad = lane >> 4, lr = lane & 15;
    const int qh = quad >> 1, c0 = (quad & 1) * 8;

    // per-lane tap offsets (bf16 units) for ks=0..4: t = 2ks + qh (t=8 shared)
    const int off0 = qh ? (1 * XSTR) : 0;
    const int off1 = qh ? (18 * XSTR + 0 * XSTR) : (2 * XSTR);
    const int off2 = qh ? (18 * XSTR + 2 * XSTR) : (18 * XSTR + 1 * XSTR);
    const int off3 = qh ? (36 * XSTR + 1 * XSTR) : (36 * XSTR + 0 * XSTR);
    const int off4 = 36 * XSTR + 2 * XSTR;

    // A1 frags for GEMM2, K=128 in 4 steps (held entire kernel, 16 VGPRs)
    short8 A1[4];
    #pragma unroll
    for (int ks = 0; ks < 4; ++ks)
        A1[ks] = *(const short8*)(w1b + lr * HID + ks * 32 + quad * 8);

    unsigned short* Hw = &Hb[w][0];

    #pragma unroll 1
    for (int nt = 0; nt < 4; ++nt) {
        const int base = ((w * 4 + nt) * 18 + lr) * XSTR + c0;
        const short8 Bf0 = *(const short8*)(xt + base + off0);
        const short8 Bf1 = *(const short8*)(xt + base + off1);
        const short8 Bf2 = *(const short8*)(xt + base + off2);
        const short8 Bf3 = *(const short8*)(xt + base + off3);
        const short8 Bf4 = *(const short8*)(xt + base + off4);

        #pragma unroll 1
        for (int q = 0; q < 4; ++q) {
            const unsigned short* w0q = w0e + (q * 32 + lr) * KEXP + quad * 8;
            #pragma unroll
            for (int mt = 0; mt < 2; ++mt) {
                const unsigned short* wrow = w0q + mt * 16 * KEXP;
                short8 a0 = *(const short8*)(wrow);
                short8 a1 = *(const short8*)(wrow + 32);
                short8 a2 = *(const short8*)(wrow + 64);
                short8 a3 = *(const short8*)(wrow + 96);
                short8 a4 = *(const short8*)(wrow + 128);
                floatx4 acc = {0.f, 0.f, 0.f, 0.f};
                acc = __builtin_amdgcn_mfma_f32_16x16x32_bf16(a0, Bf0, acc, 0, 0, 0);
                acc = __builtin_amdgcn_mfma_f32_16x16x32_bf16(a1, Bf1, acc, 0, 0, 0);
                acc = __builtin_amdgcn_mfma_f32_16x16x32_bf16(a2, Bf2, acc, 0, 0, 0);
                acc = __builtin_amdgcn_mfma_f32_16x16x32_bf16(a3, Bf3, acc, 0, 0, 0);
                acc = __builtin_amdgcn_mfma_f32_16x16x32_bf16(a4, Bf4, acc, 0, 0, 0);
                // lane holds H[pixel=lr][hid = q*32 + mt*16 + quad*4 + r]
                unsigned int lo = packtr(fmaxf(acc[0], 0.f), fmaxf(acc[1], 0.f));
                unsigned int hi = packtr(fmaxf(acc[2], 0.f), fmaxf(acc[3], 0.f));
                *(uint2*)(Hw + lr * HSTR + q * 32 + mt * 16 + quad * 4) = make_uint2(lo, hi);
            }
        }
        // RAW: cross-lane H writes must land before B reads. (WAR across nt is
        // safe: per-wave DS ops are processed in order, and this drain also
        // retires everything from the previous iteration.)
        asm volatile("s_waitcnt lgkmcnt(0)" ::: "memory");

        floatx4 dacc = {0.f, 0.f, 0.f, 0.f};
        #pragma unroll
        for (int ks = 0; ks < 4; ++ks) {
            short8 Bh = *(const short8*)(Hw + lr * HSTR + ks * 32 + quad * 8);
            dacc = __builtin_amdgcn_mfma_f32_16x16x32_bf16(A1[ks], Bh, dacc, 0, 0, 0);
        }

        // ---- epilogue: lane holds dx[pixel = w*64+nt*16+lr][o = quad*4+r] ----
        const int gy = by + w * 4 + nt, gx = bx + lr;
        const size_t pix = (size_t)b * HH * WW + (size_t)gy * WW + gx;
        const float upd = (rand_mask[pix] <= 0.5f) ? 1.f : 0.f;
        const float4 xc = *(const float4*)(x + pix * CC + quad * 4);
        float4 xn;
        xn.x = xc.x + dacc[0] * upd;
        xn.y = xc.y + dacc[1] * upd;
        xn.z = xc.z + dacc[2] * upd;
        xn.w = xc.w + dacc[3] * upd;
        *(float4*)(xn_out + pix * CC + quad * 4) = xn;
        if (quad == 0) alpha_out[pix] = xn.w;   // channel 3
    }
}

// ---------------------------------------------------------------------------
// pass2: out already holds xn; zero only dead pixels (life==0).
// ---------------------------------------------------------------------------
#define TP (TS + 2)
__global__ __launch_bounds__(256)
void pass2(const float* __restrict__ alpha, const float* __restrict__ pre,
           float* __restrict__ out)
{
    __shared__ float at2[TP][TP];
    const int tx = threadIdx.x, ty = threadIdx.y;
    const int bx = blockIdx.x * TS, by = blockIdx.y * TS, b = blockIdx.z;
    const int tid = ty * TS + tx;
    const float* ab = alpha + (size_t)b * HH * WW;

    for (int idx = tid; idx < TP * TP; idx += 256) {
        int ly = idx / TP, lx = idx % TP;
        int gy = by + ly - 1, gx = bx + lx - 1;
        float v = 0.f;
        if (gy >= 0 && gy < HH && gx >= 0 && gx < WW) v = ab[gy * WW + gx];
        at2[ly][lx] = v;
    }
    __syncthreads();

    const int ly = ty + 1, lx = tx + 1;
    float m0 = fmaxf(fmaxf(at2[ly - 1][lx - 1], at2[ly - 1][lx]), at2[ly - 1][lx + 1]);
    float m1 = fmaxf(fmaxf(at2[ly    ][lx - 1], at2[ly    ][lx]), at2[ly    ][lx + 1]);
    float m2 = fmaxf(fmaxf(at2[ly + 1][lx - 1], at2[ly + 1][lx]), at2[ly + 1][lx + 1]);
    float m = fmaxf(fmaxf(m0, m1), m2);

    const size_t pix = (size_t)b * HH * WW + (size_t)(by + ty) * WW + (bx + tx);
    const bool dead = !(m > 0.1f && pre[pix] > 0.5f);

    if (dead) {
        float4 z = make_float4(0.f, 0.f, 0.f, 0.f);
        float4* o4 = (float4*)(out + pix * CC);
        #pragma unroll
        for (int i = 0; i < 4; ++i) o4[i] = z;
    }
}

extern "C" void kernel_launch(void* const* d_in, const int* in_sizes, int n_in,
                              void* d_out, int out_size, void* d_ws, size_t ws_size,
                              hipStream_t stream) {
    const float* x  = (const float*)d_in[0];
    const float* w0 = (const float*)d_in[1];
    const float* w1 = (const float*)d_in[2];
    const float* rm = (const float*)d_in[3];
    float* out = (float*)d_out;

    float* ws    = (float*)d_ws;
    float* alpha = ws;                         // B*H*W floats
    float* pre   = ws + NPIX;                  // B*H*W floats
    unsigned short* w0e = (unsigned short*)(ws + 2 * NPIX);  // 128*160 bf16
    unsigned short* w1b = w0e + HID * KEXP;                  // 16*128 bf16

    prep<<<(HID * KEXP + 255) / 256, 256, 0, stream>>>(w0, w1, w0e, w1b);

    dim3 grid(WW / TS, HH / TS, BB);
    dim3 blk(TS, TS);
    pass1<<<grid, blk, 0, stream>>>(x, w0e, w1b, rm, out, alpha, pre);
    pass2<<<grid, blk, 0, stream>>>(alpha, pre, out);
}